// Round 7
// baseline (187.998 us; speedup 1.0000x reference)
//
#include <hip/hip_runtime.h>
#include <math.h>

// Problem dims (fixed)
#define BATCH 2048
#define NE 8
#define XIN 512
#define UU 512

typedef __attribute__((ext_vector_type(8))) short short8;   // 8 bf16
typedef __attribute__((ext_vector_type(4))) float f32x4;

__device__ inline unsigned short f2bf(float f) {
    unsigned u = __float_as_uint(f);
    u += 0x7fffu + ((u >> 16) & 1u);
    return (unsigned short)(u >> 16);
}
__device__ inline float elu1(float x) { return x > 0.f ? x : (expf(x) - 1.f); }

// ---------------------------------------------------------------------------
// Prologue: expert-input cast + alpha fp32->bf16 + gating MLP. 256 blocks.
// ---------------------------------------------------------------------------
__global__ __launch_bounds__(256) void prologue_kernel(
    const float* __restrict__ gin, const float* __restrict__ xin,
    const float* __restrict__ W0, const float* __restrict__ b0,
    const float* __restrict__ W1, const float* __restrict__ b1,
    const float* __restrict__ Wo, const float* __restrict__ bo,
    const float* __restrict__ alpha0, const float* __restrict__ alpha1,
    const float* __restrict__ alpha2,
    float* __restrict__ g, unsigned short* __restrict__ ab,
    unsigned short* __restrict__ xb0)
{
    __shared__ float xs[8][128];
    __shared__ float hs[8][128];
    __shared__ float ps2[2][8][128];
    __shared__ float lp[4][8][8];
    __shared__ float lsx[8][8];

    const int t = threadIdx.x;
    const int blk = blockIdx.x;

    // (a) expert-input cast: 4096 fp32 -> bf16 per block
    const int base4 = blk * 1024;
    #pragma unroll
    for (int q = 0; q < 4; ++q) {
        const int i4 = base4 + q * 256 + t;
        const float4 v = ((const float4*)xin)[i4];
        union { unsigned short us[4]; uint2 u2; } pk;
        pk.us[0] = f2bf(v.x); pk.us[1] = f2bf(v.y);
        pk.us[2] = f2bf(v.z); pk.us[3] = f2bf(v.w);
        ((uint2*)xb0)[i4] = pk.u2;
    }
    // (b) alpha pools fp32 -> bf16 (3 * 2^21 elems; 24 float4/thread)
    #pragma unroll
    for (int q = 0; q < 24; ++q) {
        const int vi4 = blk * 6144 + q * 256 + t;      // float4 index
        const int a = vi4 >> 19;                        // 2^19 float4 per alpha
        const int off4 = vi4 & ((1 << 19) - 1);
        const float* src = (a == 0) ? alpha0 : ((a == 1) ? alpha1 : alpha2);
        const float4 v = ((const float4*)src)[off4];
        union { unsigned short us[4]; uint2 u2; } pk;
        pk.us[0] = f2bf(v.x); pk.us[1] = f2bf(v.y);
        pk.us[2] = f2bf(v.z); pk.us[3] = f2bf(v.w);
        ((uint2*)ab)[vi4] = pk.u2;
    }
    // (c) gating MLP for rows blk*8 .. blk*8+7 (fp32 exact)
    const int c = t & 127, h = t >> 7;
    const int row0 = blk * 8;
    #pragma unroll
    for (int q = 0; q < 4; ++q)
        ((float*)xs)[q * 256 + t] = gin[row0 * 128 + q * 256 + t];
    __syncthreads();
    {
        float a8[8] = {};
        const float* Wc = W0 + c;
        #pragma unroll 8
        for (int i = h * 64; i < h * 64 + 64; ++i) {
            const float w = Wc[i * 128];
            #pragma unroll
            for (int r = 0; r < 8; ++r) a8[r] += xs[r][i] * w;
        }
        #pragma unroll
        for (int r = 0; r < 8; ++r) ps2[h][r][c] = a8[r];
    }
    __syncthreads();
    #pragma unroll
    for (int q = 0; q < 4; ++q) {
        const int o = q * 256 + t, r = o >> 7, cc = o & 127;
        hs[r][cc] = elu1(ps2[0][r][cc] + ps2[1][r][cc] + b0[cc]);
    }
    __syncthreads();
    {
        float a8[8] = {};
        const float* Wc = W1 + c;
        #pragma unroll 8
        for (int i = h * 64; i < h * 64 + 64; ++i) {
            const float w = Wc[i * 128];
            #pragma unroll
            for (int r = 0; r < 8; ++r) a8[r] += hs[r][i] * w;
        }
        #pragma unroll
        for (int r = 0; r < 8; ++r) ps2[h][r][c] = a8[r];
    }
    __syncthreads();
    #pragma unroll
    for (int q = 0; q < 4; ++q) {
        const int o = q * 256 + t, r = o >> 7, cc = o & 127;
        xs[r][cc] = elu1(ps2[0][r][cc] + ps2[1][r][cc] + b1[cc]);
    }
    __syncthreads();
    {
        const int e = t & 7, r = (t >> 3) & 7, q2 = t >> 6;
        float s = 0.f;
        #pragma unroll
        for (int i = q2 * 32; i < q2 * 32 + 32; ++i) s += xs[r][i] * Wo[i * 8 + e];
        lp[q2][r][e] = s;
    }
    __syncthreads();
    if (t < 64) {
        const int r = t >> 3, e = t & 7;
        lsx[r][e] = bo[e] + lp[0][r][e] + lp[1][r][e] + lp[2][r][e] + lp[3][r][e];
    }
    __syncthreads();
    if (t < 8) {
        float mx = lsx[t][0];
        #pragma unroll
        for (int e = 1; e < 8; ++e) mx = fmaxf(mx, lsx[t][e]);
        float s = 0.f, ex[8];
        #pragma unroll
        for (int e = 0; e < 8; ++e) { ex[e] = expf(lsx[t][e] - mx); s += ex[e]; }
        const float inv = 1.f / s;
        #pragma unroll
        for (int e = 0; e < 8; ++e) g[(row0 + t) * 8 + e] = ex[e] * inv;
    }
}

// ---------------------------------------------------------------------------
// One MoE layer: 256 blocks x 256 threads; block = 64(M) x 64(N) tile.
// All 8 experts accumulated in registers; B (alpha_l) streamed global->VGPR;
// A staged in LDS in two 32 KB K-halves, XOR-swizzled (2-way aliasing = free).
// Epilogue: exact fp32 v = sum_e g[b,e]*(acc_e + beta_e[n]); ELU+bf16 or fp32 out.
// ---------------------------------------------------------------------------
__global__ __launch_bounds__(256) void moe_layer_kernel(
    const unsigned short* __restrict__ Xc,   // bf16 activations in  (2048x512)
    unsigned short* __restrict__ Xd,         // bf16 activations out (unused if last)
    const unsigned short* __restrict__ Blay, // bf16 alpha_l [8][512][512]
    const float* __restrict__ bl,            // beta_l (8,512)
    const float* __restrict__ g,             // (2048,8)
    float* __restrict__ out, int last)
{
    __shared__ unsigned short As[64 * 256];    // 32 KB: A half-K tile, swizzled
    __shared__ float gsh[512];                 // 2 KB

    const int t = threadIdx.x;
    const int blk = blockIdx.x;
    const int wave = t >> 6, lane = t & 63;
    const int bm = blk >> 3, bn = blk & 7;   // bn==blk%8 -> same-XCD blocks share B slab
    const int m0 = bm * 64, n0 = bn * 64;
    const int fr = lane & 15, rq = lane >> 4;
    const int cl = wave * 16 + fr;           // block-local output col of this lane
    const int srow = lane >> 5;              // staging: row within pair
    const int cs = lane & 31;                // staging: stored (swizzled) chunk

    // stage g for this block's 64 rows
    gsh[t] = g[m0 * 8 + t];
    gsh[t + 256] = g[m0 * 8 + t + 256];
    // per-lane beta (col fixed per lane)
    float bt[8];
    #pragma unroll
    for (int e = 0; e < 8; ++e) bt[e] = bl[e * 512 + n0 + cl];

    // B fragment pointers: n = n0 + wave*16 + fr, k-subrow = rq*8
    const int eoff = (n0 + wave * 16 + fr) * 512 + rq * 8;
    const unsigned short* Bp[8];
    #pragma unroll
    for (int e = 0; e < 8; ++e) Bp[e] = Blay + (size_t)e * 262144 + eoff;

    f32x4 acc[8][4] = {};

    #pragma unroll
    for (int h = 0; h < 2; ++h) {
        __syncthreads();   // As free (covers gsh write on h=0, prev compute on h=1)
        // stage A half h: 64 rows x 256 k, 8 insts/wave, 2 rows per inst.
        // LDS dest is uniform-base + lane*16B; XOR swizzle applied on the GLOBAL
        // address: LDS[row][chunk cs] holds logical chunk cs^(row&7).
        #pragma unroll
        for (int it = 0; it < 8; ++it) {
            const int rpair = wave * 16 + it * 2;
            const int row = rpair + srow;
            const int c = cs ^ (row & 7);          // source chunk (8 shorts)
            const unsigned short* ga =
                Xc + (size_t)(m0 + row) * 512 + h * 256 + c * 8;
            __builtin_amdgcn_global_load_lds(
                (const __attribute__((address_space(1))) void*)ga,
                (__attribute__((address_space(3))) void*)(As + rpair * 256 + lane * 8),
                16, 0, 0);
        }
        __syncthreads();   // As ready

        #pragma unroll
        for (int kkh = 0; kkh < 256; kkh += 32) {
            const int kk = h * 256 + kkh;
            short8 af[4];
            #pragma unroll
            for (int i = 0; i < 4; ++i) {
                const int r = i * 16 + fr;
                const int c = (kkh >> 3) + rq;     // logical chunk
                af[i] = *(const short8*)(As + r * 256 + ((c ^ (r & 7)) * 8));
            }
            short8 bfv[8];
            #pragma unroll
            for (int e = 0; e < 8; ++e) bfv[e] = *(const short8*)(Bp[e] + kk);
            #pragma unroll
            for (int e = 0; e < 8; ++e)
                #pragma unroll
                for (int i = 0; i < 4; ++i)
                    acc[e][i] = __builtin_amdgcn_mfma_f32_16x16x32_bf16(
                        af[i], bfv[e], acc[e][i], 0, 0, 0);
        }
    }

    // epilogue: C/D map col=lane&15, row=(lane>>4)*4+reg  [m89-verified]
    #pragma unroll
    for (int i = 0; i < 4; ++i) {
        #pragma unroll
        for (int r = 0; r < 4; ++r) {
            const int row = i * 16 + rq * 4 + r;
            const float4 g0 = *(const float4*)(gsh + row * 8);
            const float4 g1 = *(const float4*)(gsh + row * 8 + 4);
            const float v =
                g0.x * (acc[0][i][r] + bt[0]) + g0.y * (acc[1][i][r] + bt[1]) +
                g0.z * (acc[2][i][r] + bt[2]) + g0.w * (acc[3][i][r] + bt[3]) +
                g1.x * (acc[4][i][r] + bt[4]) + g1.y * (acc[5][i][r] + bt[5]) +
                g1.z * (acc[6][i][r] + bt[6]) + g1.w * (acc[7][i][r] + bt[7]);
            const size_t oidx = (size_t)(m0 + row) * 512 + n0 + cl;
            if (last) out[oidx] = v;
            else      Xd[oidx] = f2bf(elu1(v));
        }
    }
}

// ---------------------------------------------------------------------------
extern "C" void kernel_launch(void* const* d_in, const int* in_sizes, int n_in,
                              void* d_out, int out_size, void* d_ws, size_t ws_size,
                              hipStream_t stream)
{
    (void)in_sizes; (void)n_in; (void)out_size; (void)ws_size;
    const float* gin = (const float*)d_in[0];
    const float* xin = (const float*)d_in[1];
    const float* W0  = (const float*)d_in[2];
    const float* b0  = (const float*)d_in[3];
    const float* W1  = (const float*)d_in[4];
    const float* b1  = (const float*)d_in[5];
    const float* Wo  = (const float*)d_in[6];
    const float* bo  = (const float*)d_in[7];
    const float* alpha0 = (const float*)d_in[8];
    const float* beta0  = (const float*)d_in[9];
    const float* alpha1 = (const float*)d_in[10];
    const float* beta1  = (const float*)d_in[11];
    const float* alpha2 = (const float*)d_in[12];
    const float* beta2  = (const float*)d_in[13];
    float* out = (float*)d_out;

    char* ws = (char*)d_ws;
    float* g = (float*)ws;                                      // 64 KB
    unsigned short* ab  = (unsigned short*)(ws + 65536);        // 12.58 MB
    unsigned short* xb0 = (unsigned short*)(ws + 65536 + 12582912);        // 2 MB
    unsigned short* xb1 = (unsigned short*)(ws + 65536 + 12582912 + 2097152);

    prologue_kernel<<<256, 256, 0, stream>>>(
        gin, xin, W0, b0, W1, b1, Wo, bo, alpha0, alpha1, alpha2, g, ab, xb0);

    moe_layer_kernel<<<256, 256, 0, stream>>>(
        xb0, xb1, ab,                       beta0, g, out, 0);
    moe_layer_kernel<<<256, 256, 0, stream>>>(
        xb1, xb0, ab + ((size_t)1 << 21),   beta1, g, out, 0);
    moe_layer_kernel<<<256, 256, 0, stream>>>(
        xb0, xb1, ab + ((size_t)2 << 21),   beta2, g, out, 1);
}